// Round 12
// baseline (447.375 us; speedup 1.0000x reference)
//
#include <hip/hip_runtime.h>
#include <cstdint>
#include <cstddef>

#define BN 4
#define NN 100000
#define CC 41
#define NCLS 40
#define NPROB (BN * NCLS)
#define PROP 100
#define NEGV (-1e9f)
#define IOU_T 0.3f
#define SCORE_T 0.7f
#define MAXR 4.135166556742356f
#define CAP 2048             // fallback compaction cap
#define CAPW 4096            // main window cap (LDS keys+boxes)
#define TARGET 384           // fallback window target
#define TARGETW 3072         // main window target
#define LISTCAP 26624
#define NBMPW 3125           // 100000/32
#define E07 0xBF333333u      // encf(0.7f)
#define ERHI 0xC1800000u     // encf(16.0f)
#define W0 ((unsigned long long)(ERHI - E07))
#define NT3 512              // threads in nms_finish
#define CHK 8192
#define NCHKB 4              // ceil(LISTCAP/CHK)

typedef unsigned long long ull;
typedef unsigned int uint;

__device__ __forceinline__ uint encf(float x) {
  uint u = __float_as_uint(x);
  return (u & 0x80000000u) ? ~u : (u | 0x80000000u);
}
__device__ __forceinline__ float decf(uint e) {
  uint u = (e & 0x80000000u) ? (e ^ 0x80000000u) : ~e;
  return __uint_as_float(u);
}
__device__ __forceinline__ uint binofE(ull E) {
  return (E >= (ull)ERHI) ? 255u : (uint)(((E - E07) << 8) / W0);
}
__device__ __forceinline__ ull edgeE(int b) {   // low edge of bin b
  return (ull)E07 + (((ull)b * W0 + 255ull) >> 8);
}

__device__ __forceinline__ float iou_f(float ax1, float ay1, float ax2, float ay2,
                                       float bx1, float by1, float bx2, float by2) {
  float ix1 = fmaxf(ax1, bx1), iy1 = fmaxf(ay1, by1);
  float ix2 = fminf(ax2, bx2), iy2 = fminf(ay2, by2);
  float inter = fmaxf(ix2 - ix1, 0.0f) * fmaxf(iy2 - iy1, 0.0f);
  float a1 = (ax2 - ax1) * (ay2 - ay1);
  float a2 = (bx2 - bx1) * (by2 - by1);
  return inter / fmaxf(a1 + a2 - inter, 1e-9f);
}

// serial selection from a 256-bin histogram (rare fallback path only)
__device__ __forceinline__ int select_window(const uint* h, int* lo_out) {
  uint cum = 0; int lo = 256; int act = 2;
  for (int bb = 255; bb >= 0; --bb) {
    uint nb = h[bb];
    if (nb == 0u) continue;
    if (cum + nb > CAP) {
      if (cum == 0u) { act = 1; }
      break;
    }
    cum += nb; lo = bb; act = 0;
    if (cum >= TARGET) break;
  }
  *lo_out = lo;
  return act;
}

// ---------------- Kernel A: decode + clip boxes, zero counters ----------------
__global__ void decode_kernel(const float4* __restrict__ regress,
                              const float4* __restrict__ anchors,
                              float4* __restrict__ boxes,
                              uint* __restrict__ gcnt) {
  int i = blockIdx.x * 256 + threadIdx.x;
  if (i < NPROB) gcnt[i] = 0u;
  if (i >= BN * NN) return;
  int n = i % NN;
  float4 d = regress[i];
  float4 a = anchors[n];
  float w = a.z - a.x, h = a.w - a.y;
  float cx = a.x + 0.5f * w, cy = a.y + 0.5f * h;
  float dx = d.x * 0.1f, dy = d.y * 0.1f;
  float dw = fminf(fmaxf(d.z * 0.2f, -MAXR), MAXR);
  float dh = fminf(fmaxf(d.w * 0.2f, -MAXR), MAXR);
  float pcx = cx + dx * w, pcy = cy + dy * h;
  float pw = w * expf(dw), ph = h * expf(dh);
  float4 o;
  o.x = fminf(fmaxf(pcx - 0.5f * pw, 0.0f), 1.0f);
  o.y = fminf(fmaxf(pcy - 0.5f * ph, 0.0f), 1.0f);
  o.z = fminf(fmaxf(pcx + 0.5f * pw, 0.0f), 1.0f);
  o.w = fminf(fmaxf(pcy + 0.5f * ph, 0.0f), 1.0f);
  boxes[i] = o;
}

// ---------------- Kernel B: fg + per-problem compact candidate lists (R9 proven) ----------------
__global__ void score_kernel(const float* __restrict__ logits,
                             ull* __restrict__ glist,
                             uint* __restrict__ gcnt,
                             uint* __restrict__ fgb) {
  __shared__ float lg[256 * CC];            // 42 KB
  __shared__ unsigned short wpre[NCLS][4];
  __shared__ uint cbase[NCLS];
  int b = blockIdx.y;
  int n0 = blockIdx.x * 256;
  int tid = threadIdx.x;
  int wave = tid >> 6, lane = tid & 63;
  int rows = NN - n0; if (rows > 256) rows = 256;
  int total4 = rows * CC / 4;
  const float4* src = (const float4*)(logits + ((size_t)b * NN + n0) * CC);
  float4* dst = (float4*)lg;
  for (int i = tid; i < total4; i += 256) dst[i] = src[i];
  __syncthreads();

  bool act = tid < rows;
  int n = n0 + tid;
  float bestv = 0.0f; int bestc = 0;
  if (act) {
    bestv = lg[tid * CC];
    #pragma unroll
    for (int c = 1; c < CC; ++c) {
      float v = lg[tid * CC + c];
      if (v > bestv) { bestv = v; bestc = c; }
    }
  }
  bool fg = act && (bestc > 0);
  int wbase = n0 + (tid & ~63);

  ull mfg = __ballot(fg);
  if (lane == 0 && wbase < NN) fgb[b * NBMPW + (wbase >> 5)] = (uint)mfg;
  if (lane == 32 && wbase + 32 < NN) fgb[b * NBMPW + (wbase >> 5) + 1] = (uint)(mfg >> 32);

  #pragma unroll 4
  for (int c = 1; c < CC; ++c) {
    float v = act ? lg[tid * CC + c] : 0.0f;
    ull m = __ballot(fg && (v >= SCORE_T));
    if (lane == 0) wpre[c - 1][wave] = (unsigned short)__popcll(m);
  }
  __syncthreads();

  if (tid < NCLS) {
    uint t0 = wpre[tid][0], t1 = wpre[tid][1], t2 = wpre[tid][2], t3 = wpre[tid][3];
    uint tot = t0 + t1 + t2 + t3;
    uint base = tot ? atomicAdd(&gcnt[b * NCLS + tid], tot) : 0u;
    cbase[tid] = base;
    wpre[tid][0] = 0;
    wpre[tid][1] = (unsigned short)t0;
    wpre[tid][2] = (unsigned short)(t0 + t1);
    wpre[tid][3] = (unsigned short)(t0 + t1 + t2);
  }
  __syncthreads();

  #pragma unroll 4
  for (int c = 1; c < CC; ++c) {
    float v = act ? lg[tid * CC + c] : 0.0f;
    bool elig = fg && (v >= SCORE_T);
    ull m = __ballot(elig);
    if (elig) {
      uint pos = cbase[c - 1] + wpre[c - 1][wave]
               + (uint)__popcll(m & ((1ull << lane) - 1ull));
      if (pos < LISTCAP)
        glist[(size_t)(b * NCLS + (c - 1)) * LISTCAP + pos] =
            ((ull)encf(v) << 32) | (uint)n;
    }
  }
}

// ---------------- Kernel C1: per-(problem,chunk) 256-bin histogram ----------------
__global__ void hist_kernel(const ull* __restrict__ glist,
                            const uint* __restrict__ gcnt,
                            uint* __restrict__ chist) {
  __shared__ uint h[256];
  int prob = blockIdx.y;
  int chunk = blockIdx.x;
  int tid = threadIdx.x;
  uint cnt = gcnt[prob];
  h[tid] = 0u;
  __syncthreads();
  if (cnt <= LISTCAP) {
    uint lo = chunk * CHK;
    uint hi = cnt < lo + CHK ? cnt : lo + CHK;
    const ull* list = glist + (size_t)prob * LISTCAP;
    for (uint i = lo + tid; i < hi; i += 256)
      atomicAdd(&h[binofE(list[i] >> 32)], 1u);
  }
  __syncthreads();
  chist[((size_t)prob * NCHKB + chunk) * 256 + tid] = h[tid];
}

// ---------------- Kernel C2: per-problem offsets (suffix-scan + chunk prefixes) ----------------
__global__ void offsets_kernel(const uint* __restrict__ chist,
                               const uint* __restrict__ gcnt,
                               uint* __restrict__ gcoff,
                               uint* __restrict__ gC) {
  __shared__ uint sa[256], sb[256];
  int prob = blockIdx.x;
  int tid = threadIdx.x;
  uint cnt = gcnt[prob];
  if (cnt > LISTCAP) return;  // dense fallback
  const uint* ch = chist + (size_t)prob * NCHKB * 256;
  uint h0 = ch[0 * 256 + tid], h1 = ch[1 * 256 + tid],
       h2 = ch[2 * 256 + tid], h3 = ch[3 * 256 + tid];
  gcoff[((size_t)prob * NCHKB + 0) * 256 + tid] = 0u;
  gcoff[((size_t)prob * NCHKB + 1) * 256 + tid] = h0;
  gcoff[((size_t)prob * NCHKB + 2) * 256 + tid] = h0 + h1;
  gcoff[((size_t)prob * NCHKB + 3) * 256 + tid] = h0 + h1 + h2;
  sa[tid] = h0 + h1 + h2 + h3;
  __syncthreads();
  uint* s = sa; uint* d = sb;
  for (int off = 1; off < 256; off <<= 1) {
    uint v = s[tid] + ((tid + off < 256) ? s[tid + off] : 0u);
    d[tid] = v;
    __syncthreads();
    uint* t = s; s = d; d = t;
  }
  gC[(size_t)prob * 257 + tid] = s[tid];   // C[bin] = #elements in bins >= bin
  if (tid == 0) gC[(size_t)prob * 257 + 256] = 0u;
}

// ---------------- Kernel C3: counting-sort scatter into bucketed list ----------------
__global__ void scatter_kernel(const ull* __restrict__ glist,
                               const uint* __restrict__ gcnt,
                               const uint* __restrict__ gcoff,
                               const uint* __restrict__ gC,
                               ull* __restrict__ blist) {
  __shared__ uint rank[256], startL[256], cofL[256];
  int prob = blockIdx.y;
  int chunk = blockIdx.x;
  int tid = threadIdx.x;
  uint cnt = gcnt[prob];
  if (cnt > LISTCAP) return;
  rank[tid] = 0u;
  cofL[tid] = gcoff[((size_t)prob * NCHKB + chunk) * 256 + tid];
  startL[tid] = gC[(size_t)prob * 257 + tid + 1];   // start of bin's run
  __syncthreads();
  uint lo = chunk * CHK;
  uint hi = cnt < lo + CHK ? cnt : lo + CHK;
  const ull* list = glist + (size_t)prob * LISTCAP;
  ull* bl = blist + (size_t)prob * LISTCAP;
  for (uint i = lo + tid; i < hi; i += 256) {
    ull k = list[i];
    uint bin = binofE(k >> 32);
    uint r = atomicAdd(&rank[bin], 1u);
    bl[startL[bin] + cofL[bin] + r] = k;
  }
}

// ---------------- bitonic sort descending (padded, block-wide) ----------------
__device__ void sort_desc(ull* keysL, int ncand, int tid) {
  int M = 64; while (M < ncand) M <<= 1;
  for (int i = ncand + tid; i < M; i += NT3) keysL[i] = 0ull;
  __syncthreads();
  for (int k = 2; k <= M; k <<= 1) {
    for (int j = k >> 1; j > 0; j >>= 1) {
      for (int t = tid; t < M; t += NT3) {
        int ixj = t ^ j;
        if (ixj > t) {
          ull a = keysL[t], c2 = keysL[ixj];
          bool up = ((t & k) == 0);     // up-region: descending
          if (up ? (a < c2) : (a > c2)) { keysL[t] = c2; keysL[ixj] = a; }
        }
      }
      __syncthreads();
    }
  }
}

// ---------------- block-parallel forward-suppression walk ----------------
// keysL sorted desc; boxesL indexed by key's low 15 bits; returns new nsel.
__device__ int fwalk(int ncand, int nsel,
                     const ull* keysL, const float4* boxesL, float4* selL,
                     uint* liveW, int* sh_sel, int prob,
                     int* __restrict__ oidx, float* __restrict__ osc, int tid) {
  if (ncand == 0) return nsel;
  int nw = (ncand + 31) >> 5;
  for (int i = tid; i < nw; i += NT3) {
    int rem = ncand - (i << 5);
    liveW[i] = (rem >= 32) ? 0xFFFFFFFFu : ((1u << rem) - 1u);
  }
  __syncthreads();
  // pre-suppress vs selections from earlier windows
  if (nsel > 0) {
    for (int i = tid; i < ncand; i += NT3) {
      float4 bx = boxesL[(int)(keysL[i] & 0x7FFF)];
      bool dead = false;
      for (int j = 0; j < nsel; ++j) {
        float4 sb = selL[j];
        dead = dead || (iou_f(bx.x, bx.y, bx.z, bx.w, sb.x, sb.y, sb.z, sb.w) > IOU_T);
      }
      if (dead) atomicAnd(&liveW[i >> 5], ~(1u << (i & 31)));
    }
    __syncthreads();
  }
  int pos = 0;
  while (nsel < PROP) {
    // find first live index >= pos (wave 0)
    if (tid < 64) {
      int base = pos >> 5;
      int fidx = -1;
      for (int rb = base; rb < nw && fidx < 0; rb += 64) {
        int widx = rb + tid;
        uint w = (widx < nw) ? liveW[widx] : 0u;
        if (widx == base && (pos & 31)) w &= ~((1u << (pos & 31)) - 1u);
        ull m = __ballot(w != 0u);
        if (m) {
          int fl = __ffsll(m) - 1;
          uint fw = __shfl(w, fl);
          fidx = ((rb + fl) << 5) + (__ffs(fw) - 1);
        }
      }
      if (tid == 0) *sh_sel = fidx;
    }
    __syncthreads();
    int i = *sh_sel;
    if (i < 0) break;
    ull key = keysL[i];
    float4 nb = boxesL[(int)(key & 0x7FFF)];
    if (tid == 0) {
      oidx[prob * PROP + nsel] = 131071 - (int)((key >> 15) & 0x1FFFF);
      osc [prob * PROP + nsel] = decf((uint)(key >> 32));
      selL[nsel] = nb;
      atomicAnd(&liveW[i >> 5], ~(1u << (i & 31)));
    }
    // suppress forward vs the newly selected box
    for (int k = i + 1 + tid; k < ncand; k += NT3) {
      if ((liveW[k >> 5] >> (k & 31)) & 1u) {
        float4 cb = boxesL[(int)(keysL[k] & 0x7FFF)];
        if (iou_f(cb.x, cb.y, cb.z, cb.w, nb.x, nb.y, nb.z, nb.w) > IOU_T)
          atomicAnd(&liveW[k >> 5], ~(1u << (k & 31)));
      }
    }
    nsel++;
    pos = i + 1;
    __syncthreads();
  }
  return nsel;
}

// ---------------- compact + sort + fwalk one window (fallback path) ----------------
__device__ int process_window(ull WLO, ull WUP, int idxbin,
                              bool dense, uint rs, uint re,
                              const ull* list, const float* lcol,
                              const uint* fgp, const float4* bx4,
                              ull* keysL, float4* boxesL, float4* selL,
                              uint* liveW, int* sh_cnt, int* sh_sel,
                              int nsel, int prob, int* __restrict__ oidx,
                              float* __restrict__ osc, int tid) {
  __syncthreads();
  if (tid == 0) *sh_cnt = 0;
  __syncthreads();
  if (!dense) {
    for (uint i = rs + tid; i < re; i += NT3) {
      ull k = list[i];
      ull E = k >> 32;
      uint idx = (uint)(k & 0xFFFFFFFFu);
      if (E >= WLO && E < WUP && (idxbin < 0 || (int)(idx >> 9) == idxbin)) {
        int slot = atomicAdd(sh_cnt, 1);
        if (slot < CAP) {
          keysL[slot] = (E << 32)
                      | ((ull)((131071u - idx) & 0x1FFFFu) << 15)
                      | (ull)slot;
          boxesL[slot] = bx4[idx];
        }
      }
    }
  } else {
    for (int i = tid; i < NN; i += NT3) {
      if (!((fgp[i >> 5] >> (i & 31)) & 1u)) continue;
      float s = lcol[(size_t)i * CC];
      if (s < SCORE_T) continue;
      ull E = encf(s);
      if (E >= WLO && E < WUP && (idxbin < 0 || (i >> 9) == idxbin)) {
        int slot = atomicAdd(sh_cnt, 1);
        if (slot < CAP) {
          keysL[slot] = (E << 32)
                      | ((ull)((131071u - (uint)i) & 0x1FFFFu) << 15)
                      | (ull)slot;
          boxesL[slot] = bx4[i];
        }
      }
    }
  }
  __syncthreads();
  int ncand = *sh_cnt; if (ncand > CAP) ncand = CAP;
  if (ncand == 0) return nsel;
  sort_desc(keysL, ncand, tid);
  return fwalk(ncand, nsel, keysL, boxesL, selL, liveW, sh_sel, prob, oidx, osc, tid);
}

// ---------------- exact processing of encoded range [Rlo0, Rhi0) ----------------
__device__ int fallback_range(ull Rlo0, ull Rhi0,
                              bool dense, uint rs, uint re,
                              const ull* list, const float* lcol,
                              const uint* fgp, const float4* bx4,
                              ull* keysL, float4* boxesL, float4* selL,
                              uint* liveW, uint* subh,
                              int* sh_cnt, int* sh_sel, int* sh_a, int* sh_b,
                              int nsel, int prob, int* __restrict__ oidx,
                              float* __restrict__ osc, int tid) {
  ull EHIl = Rhi0;
  for (int round = 0; round < 300 && nsel < PROP; ++round) {
    ull Rlo = Rlo0, Rhi = EHIl;
    int action; int bsel;
    ull WLO = 0, WUP = 0, E0 = 0;
    bool idxm = false;
    while (true) {
      for (int i = tid; i < 256; i += NT3) subh[i] = 0u;
      __syncthreads();
      ull W = Rhi - Rlo;
      if (!dense) {
        for (uint i = rs + tid; i < re; i += NT3) {
          ull E = list[i] >> 32;
          if (E >= Rlo && E < Rhi)
            atomicAdd(&subh[(uint)(((E - Rlo) << 8) / W)], 1u);
        }
      } else {
        for (int i = tid; i < NN; i += NT3) {
          if (!((fgp[i >> 5] >> (i & 31)) & 1u)) continue;
          float s = lcol[(size_t)i * CC];
          if (s < SCORE_T) continue;
          ull E = encf(s);
          if (E >= Rlo && E < Rhi)
            atomicAdd(&subh[(uint)(((E - Rlo) << 8) / W)], 1u);
        }
      }
      __syncthreads();
      if (tid == 0) {
        int lo;
        int act = select_window(subh, &lo);
        int rb = -1;
        if (act == 1) {
          for (int bb = 255; bb >= 0; --bb) if (subh[bb]) { rb = bb; break; }
        }
        *sh_a = act; *sh_b = (act == 1) ? rb : lo;
      }
      __syncthreads();
      action = *sh_a; bsel = *sh_b;
      __syncthreads();
      if (action == 2) break;
      if (action == 0) {
        WLO = Rlo + (((ull)bsel * W + 255ull) >> 8);
        WUP = Rhi;
        break;
      }
      ull nRlo = Rlo + (((ull)bsel * W + 255ull) >> 8);
      ull nRhi = Rlo + (((ull)(bsel + 1) * W + 255ull) >> 8);
      if (nRhi > Rhi) nRhi = Rhi;
      Rlo = nRlo; Rhi = nRhi;
      if (Rhi - Rlo <= 1ull) { idxm = true; E0 = Rlo; break; }
    }
    if (action == 2) break;
    if (!idxm) {
      nsel = process_window(WLO, WUP, -1, dense, rs, re, list, lcol, fgp, bx4,
                            keysL, boxesL, selL, liveW, sh_cnt, sh_sel,
                            nsel, prob, oidx, osc, tid);
      EHIl = WLO;
    } else {
      for (int ib = 0; ib < 256 && nsel < PROP; ++ib)
        nsel = process_window(E0, E0 + 1ull, ib, dense, rs, re, list, lcol, fgp, bx4,
                              keysL, boxesL, selL, liveW, sh_cnt, sh_sel,
                              nsel, prob, oidx, osc, tid);
      EHIl = E0;
    }
  }
  return nsel;
}

// ---------------- Kernel C4: big-window sorted forward-suppression NMS ----------------
__launch_bounds__(NT3)
__global__ void nms_finish(const ull* __restrict__ blist,
                           const uint* __restrict__ gcnt,
                           const float* __restrict__ logits,
                           const uint* __restrict__ fgb,
                           const float4* __restrict__ boxes,
                           const uint* __restrict__ gC,
                           int* __restrict__ oidx, float* __restrict__ osc) {
  __shared__ uint CL[257];
  __shared__ uint subh[256];
  __shared__ ull keysL[CAPW];               // 32 KB
  __shared__ float4 boxesL[CAPW];           // 64 KB
  __shared__ float4 selL[PROP];
  __shared__ uint liveW[CAPW / 32];         // 512 B
  __shared__ int sh_cnt, sh_sel, sh_a, sh_b, sh_m;

  int prob = blockIdx.x;
  int b = prob / NCLS;
  int c1 = prob % NCLS + 1;
  int tid = threadIdx.x;

  uint cnt = gcnt[prob];
  bool dense = cnt > LISTCAP;
  const ull* bl = blist + (size_t)prob * LISTCAP;
  const float4* bx4 = boxes + (size_t)b * NN;
  const float* lcol = logits + (size_t)b * NN * CC + c1;
  const uint* fgp = fgb + b * NBMPW;

  int nsel = 0;

  if (dense) {
    nsel = fallback_range(E07, 1ull << 32, true, 0, 0, bl, lcol, fgp, bx4,
                          keysL, boxesL, selL, liveW, subh,
                          &sh_cnt, &sh_sel, &sh_a, &sh_b,
                          0, prob, oidx, osc, tid);
  } else {
    for (int i = tid; i < 257; i += NT3) CL[i] = gC[(size_t)prob * 257 + i];
    __syncthreads();
    int hibin = 256;
    while (nsel < PROP && hibin > 0) {
      if (tid == 0) sh_m = -1;
      __syncthreads();
      if (tid < 256 && tid < hibin && (CL[tid] - CL[hibin]) >= TARGETW)
        atomicMax(&sh_m, tid);
      __syncthreads();
      if (tid == 0) {
        int bm = sh_m; int act, lo;
        if (bm < 0) {
          uint W = CL[0] - CL[hibin];
          act = W ? 0 : 2; lo = 0;
        } else {
          uint W = CL[bm] - CL[hibin];
          if (W <= CAPW) { act = 0; lo = bm; }
          else {
            uint W2 = CL[bm + 1] - CL[hibin];
            if (W2) { act = 0; lo = bm + 1; }
            else { act = 1; lo = bm; }
          }
        }
        sh_a = act; sh_b = lo;
      }
      __syncthreads();
      int act = sh_a, lo = sh_b;
      __syncthreads();
      if (act == 2) break;
      if (act == 0) {
        uint rs = CL[hibin];
        int ncand = (int)(CL[lo] - CL[hibin]);
        for (int i = tid; i < ncand; i += NT3) {
          ull k = bl[rs + i];
          uint idx = (uint)(k & 0xFFFFFFFFu);
          keysL[i] = ((k >> 32) << 32)
                   | ((ull)((131071u - idx) & 0x1FFFFu) << 15)
                   | (ull)i;
          boxesL[i] = bx4[idx];
        }
        __syncthreads();
        sort_desc(keysL, ncand, tid);
        nsel = fwalk(ncand, nsel, keysL, boxesL, selL, liveW, &sh_sel,
                     prob, oidx, osc, tid);
        hibin = lo;
      } else {
        // refine: single bin 'lo' exceeds CAPW — contiguous run, value-refined exactly
        uint rs = CL[lo + 1], re = CL[lo];
        ull Rlo = edgeE(lo);
        ull Rhi = (lo == 255) ? (1ull << 32) : edgeE(lo + 1);
        nsel = fallback_range(Rlo, Rhi, false, rs, re, bl, lcol, fgp, bx4,
                              keysL, boxesL, selL, liveW, subh,
                              &sh_cnt, &sh_sel, &sh_a, &sh_b,
                              nsel, prob, oidx, osc, tid);
        hibin = lo;
      }
    }
  }

  __syncthreads();
  for (int p = nsel + tid; p < PROP; p += NT3) {
    oidx[prob * PROP + p] = -1;
    osc [prob * PROP + p] = NEGV;
  }
}

// ---------------- Kernel D: per-batch top-100 of 4000 (bitonic, 1024 thr) + gather ----------------
__global__ void topk_kernel(const float* __restrict__ logits,
                            const float4* __restrict__ boxes,
                            const int* __restrict__ oidx,
                            const float* __restrict__ osc,
                            float* __restrict__ out) {
  __shared__ ull keys[4096];  // 32 KB
  int b = blockIdx.x;
  int tid = threadIdx.x;
  for (int i = tid; i < 4096; i += 1024) {
    ull key = 0ull;
    if (i < NCLS * PROP) {
      float sc = osc[b * NCLS * PROP + i];
      key = ((ull)encf(sc) << 32) | (uint)(~i);
    }
    keys[i] = ~key;
  }
  __syncthreads();
  for (int k = 2; k <= 4096; k <<= 1) {
    for (int j = k >> 1; j > 0; j >>= 1) {
      for (int t = tid; t < 4096; t += 1024) {
        int ixj = t ^ j;
        if (ixj > t) {
          ull a = keys[t], c2 = keys[ixj];
          bool up = ((t & k) == 0);
          if ((a > c2) == up) { keys[t] = c2; keys[ixj] = a; }
        }
      }
      __syncthreads();
    }
  }
  if (tid < PROP) {
    ull key = ~keys[tid];
    uint e = (uint)(key >> 32);
    float sc = decf(e);
    bool ok = sc > 0.5f * NEGV;
    int kk = (int)(~(uint)key);
    if (kk < 0 || kk >= NCLS * PROP) kk = 0;
    int idx = ok ? oidx[b * NCLS * PROP + kk] : 0;
    if (idx < 0) idx = 0;
    float m = ok ? 1.0f : 0.0f;
    const float* lp = logits + ((size_t)b * NN + idx) * CC;
    float* outl = out + ((size_t)b * PROP + tid) * CC;
    #pragma unroll
    for (int c = 0; c < CC; ++c) outl[c] = lp[c] * m;
    float4 bb = boxes[(size_t)b * NN + idx];
    float* outb = out + (size_t)BN * PROP * CC + ((size_t)b * PROP + tid) * 4;
    outb[0] = bb.x * m; outb[1] = bb.y * m; outb[2] = bb.z * m; outb[3] = bb.w * m;
  }
}

extern "C" void kernel_launch(void* const* d_in, const int* in_sizes, int n_in,
                              void* d_out, int out_size, void* d_ws, size_t ws_size,
                              hipStream_t stream) {
  const float* logits  = (const float*)d_in[0];  // (4,100000,41)
  const float* regress = (const float*)d_in[1];  // (4,100000,4)
  const float* anchors = (const float*)d_in[2];  // (100000,4)
  float* out = (float*)d_out;

  char* ws = (char*)d_ws;
  size_t off = 0;
  float4* boxes = (float4*)(ws + off);  off += (size_t)BN * NN * 16;
  ull* glist = (ull*)(ws + off);        off += (size_t)NPROB * LISTCAP * 8;
  ull* blist = (ull*)(ws + off);        off += (size_t)NPROB * LISTCAP * 8;
  uint* gcnt = (uint*)(ws + off);       off += NPROB * 4;
  uint* fgb  = (uint*)(ws + off);       off += BN * NBMPW * 4;
  float* osc = (float*)(ws + off);      off += NPROB * PROP * 4;
  int*   oidx = (int*)(ws + off);       off += NPROB * PROP * 4;
  uint* chist = (uint*)(ws + off);      off += (size_t)NPROB * NCHKB * 256 * 4;
  uint* gcoff = (uint*)(ws + off);      off += (size_t)NPROB * NCHKB * 256 * 4;
  uint* gC   = (uint*)(ws + off);       off += (size_t)NPROB * 257 * 4;

  decode_kernel<<<(BN * NN + 255) / 256, 256, 0, stream>>>(
      (const float4*)regress, (const float4*)anchors, boxes, gcnt);
  score_kernel<<<dim3((NN + 255) / 256, BN), 256, 0, stream>>>(logits, glist, gcnt, fgb);
  hist_kernel<<<dim3(NCHKB, NPROB), 256, 0, stream>>>(glist, gcnt, chist);
  offsets_kernel<<<NPROB, 256, 0, stream>>>(chist, gcnt, gcoff, gC);
  scatter_kernel<<<dim3(NCHKB, NPROB), 256, 0, stream>>>(glist, gcnt, gcoff, gC, blist);
  nms_finish<<<NPROB, NT3, 0, stream>>>(blist, gcnt, logits, fgb, boxes, gC, oidx, osc);
  topk_kernel<<<BN, 1024, 0, stream>>>(logits, boxes, oidx, osc, out);
}

// Round 13
// 405.874 us; speedup vs baseline: 1.1023x; 1.1023x over previous
//
#include <hip/hip_runtime.h>
#include <cstdint>
#include <cstddef>

#define BN 4
#define NN 100000
#define CC 41
#define NCLS 40
#define NPROB (BN * NCLS)
#define PROP 100
#define NEGV (-1e9f)
#define IOU_T 0.3f
#define SCORE_T 0.7f
#define MAXR 4.135166556742356f
#define CAP 2048
#define TARGET 384
#define LISTCAP 26624
#define NBMPW 3125           // 100000/32
#define E07 0xBF333333u      // encf(0.7f)
#define ERHI 0xC1800000u     // encf(16.0f)
#define W0 ((unsigned long long)(ERHI - E07))
#define NT3 512              // threads in nms_finish
#define CHK 8192
#define NCHKB 4              // ceil(LISTCAP/CHK)

typedef unsigned long long ull;
typedef unsigned int uint;

__device__ __forceinline__ uint encf(float x) {
  uint u = __float_as_uint(x);
  return (u & 0x80000000u) ? ~u : (u | 0x80000000u);
}
__device__ __forceinline__ float decf(uint e) {
  uint u = (e & 0x80000000u) ? (e ^ 0x80000000u) : ~e;
  return __uint_as_float(u);
}
__device__ __forceinline__ uint binofE(ull E) {
  return (E >= (ull)ERHI) ? 255u : (uint)(((E - E07) << 8) / W0);
}
__device__ __forceinline__ ull edgeE(int b) {   // low edge of bin b
  return (ull)E07 + (((ull)b * W0 + 255ull) >> 8);
}

__device__ __forceinline__ float iou_f(float ax1, float ay1, float ax2, float ay2,
                                       float bx1, float by1, float bx2, float by2) {
  float ix1 = fmaxf(ax1, bx1), iy1 = fmaxf(ay1, by1);
  float ix2 = fminf(ax2, bx2), iy2 = fminf(ay2, by2);
  float inter = fmaxf(ix2 - ix1, 0.0f) * fmaxf(iy2 - iy1, 0.0f);
  float a1 = (ax2 - ax1) * (ay2 - ay1);
  float a2 = (bx2 - bx1) * (by2 - by1);
  return inter / fmaxf(a1 + a2 - inter, 1e-9f);
}

// serial selection from a 256-bin histogram (rare fallback path only)
__device__ __forceinline__ int select_window(const uint* h, int* lo_out) {
  uint cum = 0; int lo = 256; int act = 2;
  for (int bb = 255; bb >= 0; --bb) {
    uint nb = h[bb];
    if (nb == 0u) continue;
    if (cum + nb > CAP) {
      if (cum == 0u) { act = 1; }
      break;
    }
    cum += nb; lo = bb; act = 0;
    if (cum >= TARGET) break;
  }
  *lo_out = lo;
  return act;
}

// ---------------- Kernel A: decode + clip boxes, zero counters ----------------
__global__ void decode_kernel(const float4* __restrict__ regress,
                              const float4* __restrict__ anchors,
                              float4* __restrict__ boxes,
                              uint* __restrict__ gcnt) {
  int i = blockIdx.x * 256 + threadIdx.x;
  if (i < NPROB) gcnt[i] = 0u;
  if (i >= BN * NN) return;
  int n = i % NN;
  float4 d = regress[i];
  float4 a = anchors[n];
  float w = a.z - a.x, h = a.w - a.y;
  float cx = a.x + 0.5f * w, cy = a.y + 0.5f * h;
  float dx = d.x * 0.1f, dy = d.y * 0.1f;
  float dw = fminf(fmaxf(d.z * 0.2f, -MAXR), MAXR);
  float dh = fminf(fmaxf(d.w * 0.2f, -MAXR), MAXR);
  float pcx = cx + dx * w, pcy = cy + dy * h;
  float pw = w * expf(dw), ph = h * expf(dh);
  float4 o;
  o.x = fminf(fmaxf(pcx - 0.5f * pw, 0.0f), 1.0f);
  o.y = fminf(fmaxf(pcy - 0.5f * ph, 0.0f), 1.0f);
  o.z = fminf(fmaxf(pcx + 0.5f * pw, 0.0f), 1.0f);
  o.w = fminf(fmaxf(pcy + 0.5f * ph, 0.0f), 1.0f);
  boxes[i] = o;
}

// ---------------- Kernel B: fg + per-problem compact candidate lists (R9 proven) ----------------
__global__ void score_kernel(const float* __restrict__ logits,
                             ull* __restrict__ glist,
                             uint* __restrict__ gcnt,
                             uint* __restrict__ fgb) {
  __shared__ float lg[256 * CC];            // 42 KB
  __shared__ unsigned short wpre[NCLS][4];
  __shared__ uint cbase[NCLS];
  int b = blockIdx.y;
  int n0 = blockIdx.x * 256;
  int tid = threadIdx.x;
  int wave = tid >> 6, lane = tid & 63;
  int rows = NN - n0; if (rows > 256) rows = 256;
  int total4 = rows * CC / 4;
  const float4* src = (const float4*)(logits + ((size_t)b * NN + n0) * CC);
  float4* dst = (float4*)lg;
  for (int i = tid; i < total4; i += 256) dst[i] = src[i];
  __syncthreads();

  bool act = tid < rows;
  int n = n0 + tid;
  float bestv = 0.0f; int bestc = 0;
  if (act) {
    bestv = lg[tid * CC];
    #pragma unroll
    for (int c = 1; c < CC; ++c) {
      float v = lg[tid * CC + c];
      if (v > bestv) { bestv = v; bestc = c; }
    }
  }
  bool fg = act && (bestc > 0);
  int wbase = n0 + (tid & ~63);

  ull mfg = __ballot(fg);
  if (lane == 0 && wbase < NN) fgb[b * NBMPW + (wbase >> 5)] = (uint)mfg;
  if (lane == 32 && wbase + 32 < NN) fgb[b * NBMPW + (wbase >> 5) + 1] = (uint)(mfg >> 32);

  #pragma unroll 4
  for (int c = 1; c < CC; ++c) {
    float v = act ? lg[tid * CC + c] : 0.0f;
    ull m = __ballot(fg && (v >= SCORE_T));
    if (lane == 0) wpre[c - 1][wave] = (unsigned short)__popcll(m);
  }
  __syncthreads();

  if (tid < NCLS) {
    uint t0 = wpre[tid][0], t1 = wpre[tid][1], t2 = wpre[tid][2], t3 = wpre[tid][3];
    uint tot = t0 + t1 + t2 + t3;
    uint base = tot ? atomicAdd(&gcnt[b * NCLS + tid], tot) : 0u;
    cbase[tid] = base;
    wpre[tid][0] = 0;
    wpre[tid][1] = (unsigned short)t0;
    wpre[tid][2] = (unsigned short)(t0 + t1);
    wpre[tid][3] = (unsigned short)(t0 + t1 + t2);
  }
  __syncthreads();

  #pragma unroll 4
  for (int c = 1; c < CC; ++c) {
    float v = act ? lg[tid * CC + c] : 0.0f;
    bool elig = fg && (v >= SCORE_T);
    ull m = __ballot(elig);
    if (elig) {
      uint pos = cbase[c - 1] + wpre[c - 1][wave]
               + (uint)__popcll(m & ((1ull << lane) - 1ull));
      if (pos < LISTCAP)
        glist[(size_t)(b * NCLS + (c - 1)) * LISTCAP + pos] =
            ((ull)encf(v) << 32) | (uint)n;
    }
  }
}

// ---------------- Kernel C1: per-(problem,chunk) 256-bin histogram ----------------
__global__ void hist_kernel(const ull* __restrict__ glist,
                            const uint* __restrict__ gcnt,
                            uint* __restrict__ chist) {
  __shared__ uint h[256];
  int prob = blockIdx.y;
  int chunk = blockIdx.x;
  int tid = threadIdx.x;
  uint cnt = gcnt[prob];
  h[tid] = 0u;
  __syncthreads();
  if (cnt <= LISTCAP) {
    uint lo = chunk * CHK;
    uint hi = cnt < lo + CHK ? cnt : lo + CHK;
    const ull* list = glist + (size_t)prob * LISTCAP;
    for (uint i = lo + tid; i < hi; i += 256)
      atomicAdd(&h[binofE(list[i] >> 32)], 1u);
  }
  __syncthreads();
  chist[((size_t)prob * NCHKB + chunk) * 256 + tid] = h[tid];
}

// ---------------- Kernel C2: per-problem offsets (suffix-scan + chunk prefixes) ----------------
__global__ void offsets_kernel(const uint* __restrict__ chist,
                               const uint* __restrict__ gcnt,
                               uint* __restrict__ gcoff,
                               uint* __restrict__ gC) {
  __shared__ uint sa[256], sb[256];
  int prob = blockIdx.x;
  int tid = threadIdx.x;
  uint cnt = gcnt[prob];
  if (cnt > LISTCAP) return;  // dense fallback
  const uint* ch = chist + (size_t)prob * NCHKB * 256;
  uint h0 = ch[0 * 256 + tid], h1 = ch[1 * 256 + tid],
       h2 = ch[2 * 256 + tid], h3 = ch[3 * 256 + tid];
  gcoff[((size_t)prob * NCHKB + 0) * 256 + tid] = 0u;
  gcoff[((size_t)prob * NCHKB + 1) * 256 + tid] = h0;
  gcoff[((size_t)prob * NCHKB + 2) * 256 + tid] = h0 + h1;
  gcoff[((size_t)prob * NCHKB + 3) * 256 + tid] = h0 + h1 + h2;
  sa[tid] = h0 + h1 + h2 + h3;
  __syncthreads();
  uint* s = sa; uint* d = sb;
  for (int off = 1; off < 256; off <<= 1) {
    uint v = s[tid] + ((tid + off < 256) ? s[tid + off] : 0u);
    d[tid] = v;
    __syncthreads();
    uint* t = s; s = d; d = t;
  }
  gC[(size_t)prob * 257 + tid] = s[tid];   // C[bin] = #elements in bins >= bin
  if (tid == 0) gC[(size_t)prob * 257 + 256] = 0u;
}

// ---------------- Kernel C3: counting-sort scatter into bucketed list ----------------
__global__ void scatter_kernel(const ull* __restrict__ glist,
                               const uint* __restrict__ gcnt,
                               const uint* __restrict__ gcoff,
                               const uint* __restrict__ gC,
                               ull* __restrict__ blist) {
  __shared__ uint rank[256], startL[256], cofL[256];
  int prob = blockIdx.y;
  int chunk = blockIdx.x;
  int tid = threadIdx.x;
  uint cnt = gcnt[prob];
  if (cnt > LISTCAP) return;
  rank[tid] = 0u;
  cofL[tid] = gcoff[((size_t)prob * NCHKB + chunk) * 256 + tid];
  startL[tid] = gC[(size_t)prob * 257 + tid + 1];   // start of bin's run
  __syncthreads();
  uint lo = chunk * CHK;
  uint hi = cnt < lo + CHK ? cnt : lo + CHK;
  const ull* list = glist + (size_t)prob * LISTCAP;
  ull* bl = blist + (size_t)prob * LISTCAP;
  for (uint i = lo + tid; i < hi; i += 256) {
    ull k = list[i];
    uint bin = binofE(k >> 32);
    uint r = atomicAdd(&rank[bin], 1u);
    bl[startL[bin] + cofL[bin] + r] = k;
  }
}

// ---------------- Kernel C3b: sort each bin-run in place (wide, parallel) ----------------
// After this, blist[0..cnt) is globally sorted desc by (score, then lower idx),
// except bins with size > CAP (left unsorted; handled by fallback in nms_finish).
__global__ void sortbins_kernel(ull* __restrict__ blist,
                                const uint* __restrict__ gcnt,
                                const uint* __restrict__ gC) {
  __shared__ ull kb[CAP];   // 16 KB
  int prob = blockIdx.y;
  int bin = blockIdx.x;
  int tid = threadIdx.x;
  uint cnt = gcnt[prob];
  if (cnt > LISTCAP) return;
  uint rs = gC[(size_t)prob * 257 + bin + 1];
  uint re = gC[(size_t)prob * 257 + bin];
  int sz = (int)(re - rs);
  if (sz < 2 || sz > CAP) return;
  ull* bl = blist + (size_t)prob * LISTCAP;
  // transform: desc sort of (E<<32)|~idx == desc score, asc idx on ties
  for (int i = tid; i < sz; i += 256) {
    ull k = bl[rs + i];
    kb[i] = (k & 0xFFFFFFFF00000000ull) | (ull)(uint)(~(uint)k);
  }
  int M = 64; while (M < sz) M <<= 1;
  for (int i = sz + tid; i < M; i += 256) kb[i] = 0ull;
  __syncthreads();
  for (int k = 2; k <= M; k <<= 1) {
    for (int j = k >> 1; j > 0; j >>= 1) {
      for (int t = tid; t < M; t += 256) {
        int ixj = t ^ j;
        if (ixj > t) {
          ull a = kb[t], c2 = kb[ixj];
          bool up = ((t & k) == 0);
          if (up ? (a < c2) : (a > c2)) { kb[t] = c2; kb[ixj] = a; }
        }
      }
      __syncthreads();
    }
  }
  for (int i = tid; i < sz; i += 256) {
    ull t = kb[i];
    bl[rs + i] = (t & 0xFFFFFFFF00000000ull) | (ull)(uint)(~(uint)t);
  }
}

// ---------------- sort + walk on LDS window (fallback path, R9 proven) ----------------
__device__ int sort_walk(int ncand, int nsel,
                         ull* keysL, float4* boxesL, float4* selL,
                         int* sh_nsel, int prob, int* __restrict__ oidx,
                         float* __restrict__ osc, int tid) {
  if (ncand == 0) return nsel;
  int M = 64; while (M < ncand) M <<= 1;
  for (int i = ncand + tid; i < M; i += NT3) keysL[i] = 0ull;
  __syncthreads();
  for (int k = 2; k <= M; k <<= 1) {
    for (int j = k >> 1; j > 0; j >>= 1) {
      for (int t = tid; t < M; t += NT3) {
        int ixj = t ^ j;
        if (ixj > t) {
          ull a = keysL[t], c2 = keysL[ixj];
          bool up = ((t & k) == 0);     // up-region: descending
          if (up ? (a < c2) : (a > c2)) { keysL[t] = c2; keysL[ixj] = a; }
        }
      }
      __syncthreads();
    }
  }
  if (tid < 64) {
    int lane = tid;
    int ns = nsel;
    for (int base = 0; base < ncand && ns < PROP; base += 64) {
      int i = base + lane;
      bool valid = i < ncand;
      ull key = valid ? keysL[i] : 0ull;
      int slot = (int)(key & 0x7FFF);
      float4 bx = boxesL[valid ? slot : 0];
      float sc = decf((uint)(key >> 32));
      int aidx = 131071 - (int)((key >> 15) & 0x1FFFF);
      bool supp = false;
      for (int j = 0; j < ns; ++j) {
        float4 sb = selL[j];
        supp = supp || (iou_f(bx.x, bx.y, bx.z, bx.w, sb.x, sb.y, sb.z, sb.w) > IOU_T);
      }
      ull live = __ballot(valid && !supp);
      while (live && ns < PROP) {
        int kk = __ffsll(live) - 1;
        float x1 = __shfl(bx.x, kk), y1 = __shfl(bx.y, kk);
        float x2 = __shfl(bx.z, kk), y2 = __shfl(bx.w, kk);
        float ksc = __shfl(sc, kk);
        int kidx = __shfl(aidx, kk);
        if (lane == 0) {
          oidx[prob * PROP + ns] = kidx;
          osc [prob * PROP + ns] = ksc;
          selL[ns] = make_float4(x1, y1, x2, y2);
        }
        ns++;
        if (lane > kk && valid && !supp)
          supp = iou_f(bx.x, bx.y, bx.z, bx.w, x1, y1, x2, y2) > IOU_T;
        live = __ballot(valid && !supp) & ~((2ull << kk) - 1ull);
      }
    }
    if (lane == 0) *sh_nsel = ns;
  }
  __syncthreads();
  return *sh_nsel;
}

// ---------------- stream walk over a globally-sorted run of blist ----------------
__device__ int walk_run(uint rs, uint re, int nsel,
                        const ull* __restrict__ bl, const float4* __restrict__ bx4,
                        float4* selL, int* sh_nsel, int prob,
                        int* __restrict__ oidx, float* __restrict__ osc, int tid) {
  if (re <= rs) return nsel;
  if (tid < 64) {
    int lane = tid;
    int ns = nsel;
    // preload first batch
    uint i0 = rs + lane;
    bool v0 = i0 < re;
    ull key = v0 ? bl[i0] : 0ull;
    float4 bx = v0 ? bx4[(uint)key] : make_float4(0.f, 0.f, 0.f, 0.f);
    for (uint base = rs; base < re && ns < PROP; base += 64) {
      // prefetch next batch
      uint i1 = base + 64 + lane;
      bool v1 = i1 < re;
      ull nkey = v1 ? bl[i1] : 0ull;
      bool valid = (base + lane) < re;
      uint aidx = (uint)key;
      float sc = decf((uint)(key >> 32));
      bool supp = false;
      for (int j = 0; j < ns; ++j) {
        float4 sb = selL[j];
        supp = supp || (iou_f(bx.x, bx.y, bx.z, bx.w, sb.x, sb.y, sb.z, sb.w) > IOU_T);
      }
      ull live = __ballot(valid && !supp);
      while (live && ns < PROP) {
        int kk = __ffsll(live) - 1;
        float x1 = __shfl(bx.x, kk), y1 = __shfl(bx.y, kk);
        float x2 = __shfl(bx.z, kk), y2 = __shfl(bx.w, kk);
        float ksc = __shfl(sc, kk);
        int kidx = __shfl((int)aidx, kk);
        if (lane == 0) {
          oidx[prob * PROP + ns] = kidx;
          osc [prob * PROP + ns] = ksc;
          selL[ns] = make_float4(x1, y1, x2, y2);
        }
        ns++;
        if (lane > kk && valid && !supp)
          supp = iou_f(bx.x, bx.y, bx.z, bx.w, x1, y1, x2, y2) > IOU_T;
        live = __ballot(valid && !supp) & ~((2ull << kk) - 1ull);
      }
      float4 nbx = v1 ? bx4[(uint)nkey] : make_float4(0.f, 0.f, 0.f, 0.f);
      key = nkey; bx = nbx;
    }
    if (lane == 0) *sh_nsel = ns;
  }
  __syncthreads();
  return *sh_nsel;
}

// ---------------- compact + sort + walk one window (fallback path) ----------------
__device__ int process_window(ull WLO, ull WUP, int idxbin,
                              bool dense, uint rs, uint re,
                              const ull* list, const float* lcol,
                              const uint* fgp, const float4* bx4,
                              ull* keysL, float4* boxesL, float4* selL,
                              int* sh_cnt, int* sh_nsel,
                              int nsel, int prob, int* __restrict__ oidx,
                              float* __restrict__ osc, int tid) {
  __syncthreads();
  if (tid == 0) *sh_cnt = 0;
  __syncthreads();
  if (!dense) {
    for (uint i = rs + tid; i < re; i += NT3) {
      ull k = list[i];
      ull E = k >> 32;
      uint idx = (uint)(k & 0xFFFFFFFFu);
      if (E >= WLO && E < WUP && (idxbin < 0 || (int)(idx >> 9) == idxbin)) {
        int slot = atomicAdd(sh_cnt, 1);
        if (slot < CAP) {
          keysL[slot] = (E << 32)
                      | ((ull)((131071u - idx) & 0x1FFFFu) << 15)
                      | (ull)slot;
          boxesL[slot] = bx4[idx];
        }
      }
    }
  } else {
    for (int i = tid; i < NN; i += NT3) {
      if (!((fgp[i >> 5] >> (i & 31)) & 1u)) continue;
      float s = lcol[(size_t)i * CC];
      if (s < SCORE_T) continue;
      ull E = encf(s);
      if (E >= WLO && E < WUP && (idxbin < 0 || (i >> 9) == idxbin)) {
        int slot = atomicAdd(sh_cnt, 1);
        if (slot < CAP) {
          keysL[slot] = (E << 32)
                      | ((ull)((131071u - (uint)i) & 0x1FFFFu) << 15)
                      | (ull)slot;
          boxesL[slot] = bx4[i];
        }
      }
    }
  }
  __syncthreads();
  int ncand = *sh_cnt; if (ncand > CAP) ncand = CAP;
  return sort_walk(ncand, nsel, keysL, boxesL, selL, sh_nsel, prob, oidx, osc, tid);
}

// ---------------- exact processing of encoded range [Rlo0, Rhi0) ----------------
__device__ int fallback_range(ull Rlo0, ull Rhi0,
                              bool dense, uint rs, uint re,
                              const ull* list, const float* lcol,
                              const uint* fgp, const float4* bx4,
                              ull* keysL, float4* boxesL, float4* selL,
                              uint* subh,
                              int* sh_cnt, int* sh_nsel, int* sh_a, int* sh_b,
                              int nsel, int prob, int* __restrict__ oidx,
                              float* __restrict__ osc, int tid) {
  ull EHIl = Rhi0;
  for (int round = 0; round < 300 && nsel < PROP; ++round) {
    ull Rlo = Rlo0, Rhi = EHIl;
    int action; int bsel;
    ull WLO = 0, WUP = 0, E0 = 0;
    bool idxm = false;
    while (true) {
      for (int i = tid; i < 256; i += NT3) subh[i] = 0u;
      __syncthreads();
      ull W = Rhi - Rlo;
      if (!dense) {
        for (uint i = rs + tid; i < re; i += NT3) {
          ull E = list[i] >> 32;
          if (E >= Rlo && E < Rhi)
            atomicAdd(&subh[(uint)(((E - Rlo) << 8) / W)], 1u);
        }
      } else {
        for (int i = tid; i < NN; i += NT3) {
          if (!((fgp[i >> 5] >> (i & 31)) & 1u)) continue;
          float s = lcol[(size_t)i * CC];
          if (s < SCORE_T) continue;
          ull E = encf(s);
          if (E >= Rlo && E < Rhi)
            atomicAdd(&subh[(uint)(((E - Rlo) << 8) / W)], 1u);
        }
      }
      __syncthreads();
      if (tid == 0) {
        int lo;
        int act = select_window(subh, &lo);
        int rb = -1;
        if (act == 1) {
          for (int bb = 255; bb >= 0; --bb) if (subh[bb]) { rb = bb; break; }
        }
        *sh_a = act; *sh_b = (act == 1) ? rb : lo;
      }
      __syncthreads();
      action = *sh_a; bsel = *sh_b;
      __syncthreads();
      if (action == 2) break;
      if (action == 0) {
        WLO = Rlo + (((ull)bsel * W + 255ull) >> 8);
        WUP = Rhi;
        break;
      }
      ull nRlo = Rlo + (((ull)bsel * W + 255ull) >> 8);
      ull nRhi = Rlo + (((ull)(bsel + 1) * W + 255ull) >> 8);
      if (nRhi > Rhi) nRhi = Rhi;
      Rlo = nRlo; Rhi = nRhi;
      if (Rhi - Rlo <= 1ull) { idxm = true; E0 = Rlo; break; }
    }
    if (action == 2) break;
    if (!idxm) {
      nsel = process_window(WLO, WUP, -1, dense, rs, re, list, lcol, fgp, bx4,
                            keysL, boxesL, selL, sh_cnt, sh_nsel,
                            nsel, prob, oidx, osc, tid);
      EHIl = WLO;
    } else {
      for (int ib = 0; ib < 256 && nsel < PROP; ++ib)
        nsel = process_window(E0, E0 + 1ull, ib, dense, rs, re, list, lcol, fgp, bx4,
                              keysL, boxesL, selL, sh_cnt, sh_nsel,
                              nsel, prob, oidx, osc, tid);
      EHIl = E0;
    }
  }
  return nsel;
}

// ---------------- Kernel C4: stream-walk NMS over presorted bucketed list ----------------
__launch_bounds__(NT3)
__global__ void nms_finish(const ull* __restrict__ blist,
                           const uint* __restrict__ gcnt,
                           const float* __restrict__ logits,
                           const uint* __restrict__ fgb,
                           const float4* __restrict__ boxes,
                           const uint* __restrict__ gC,
                           int* __restrict__ oidx, float* __restrict__ osc) {
  __shared__ uint CL[257];
  __shared__ uint subh[256];
  __shared__ ull keysL[CAP];                // 16 KB (fallback only)
  __shared__ float4 boxesL[CAP];            // 32 KB (fallback only)
  __shared__ float4 selL[PROP];
  __shared__ int sh_cnt, sh_nsel, sh_a, sh_b;

  int prob = blockIdx.x;
  int b = prob / NCLS;
  int c1 = prob % NCLS + 1;
  int tid = threadIdx.x;

  uint cnt = gcnt[prob];
  bool dense = cnt > LISTCAP;
  const ull* bl = blist + (size_t)prob * LISTCAP;
  const float4* bx4 = boxes + (size_t)b * NN;
  const float* lcol = logits + (size_t)b * NN * CC + c1;
  const uint* fgp = fgb + b * NBMPW;

  int nsel = 0;

  if (dense) {
    nsel = fallback_range(E07, 1ull << 32, true, 0, 0, bl, lcol, fgp, bx4,
                          keysL, boxesL, selL, subh,
                          &sh_cnt, &sh_nsel, &sh_a, &sh_b,
                          0, prob, oidx, osc, tid);
  } else {
    for (int i = tid; i < 257; i += NT3) CL[i] = gC[(size_t)prob * 257 + i];
    __syncthreads();
    int bin = 255;
    while (bin >= 0 && nsel < PROP) {
      // extend down over sorted bins (size <= CAP, incl. empty)
      int lo = bin;
      while (lo >= 0 && (CL[lo] - CL[lo + 1]) <= CAP) --lo;
      uint rs = CL[bin + 1];
      uint re = CL[lo + 1];
      if (re > rs)
        nsel = walk_run(rs, re, nsel, bl, bx4, selL, &sh_nsel, prob, oidx, osc, tid);
      if (nsel >= PROP || lo < 0) break;
      // mega-bin lo (unsorted contiguous run): exact value-refined fallback
      {
        uint mrs = CL[lo + 1], mre = CL[lo];
        ull Rlo = edgeE(lo);
        ull Rhi = (lo == 255) ? (1ull << 32) : edgeE(lo + 1);
        nsel = fallback_range(Rlo, Rhi, false, mrs, mre, bl, lcol, fgp, bx4,
                              keysL, boxesL, selL, subh,
                              &sh_cnt, &sh_nsel, &sh_a, &sh_b,
                              nsel, prob, oidx, osc, tid);
      }
      bin = lo - 1;
    }
  }

  __syncthreads();
  for (int p = nsel + tid; p < PROP; p += NT3) {
    oidx[prob * PROP + p] = -1;
    osc [prob * PROP + p] = NEGV;
  }
}

// ---------------- Kernel D: per-batch top-100 of 4000 (bitonic, 1024 thr) + gather ----------------
__global__ void topk_kernel(const float* __restrict__ logits,
                            const float4* __restrict__ boxes,
                            const int* __restrict__ oidx,
                            const float* __restrict__ osc,
                            float* __restrict__ out) {
  __shared__ ull keys[4096];  // 32 KB
  int b = blockIdx.x;
  int tid = threadIdx.x;
  for (int i = tid; i < 4096; i += 1024) {
    ull key = 0ull;
    if (i < NCLS * PROP) {
      float sc = osc[b * NCLS * PROP + i];
      key = ((ull)encf(sc) << 32) | (uint)(~i);
    }
    keys[i] = ~key;
  }
  __syncthreads();
  for (int k = 2; k <= 4096; k <<= 1) {
    for (int j = k >> 1; j > 0; j >>= 1) {
      for (int t = tid; t < 4096; t += 1024) {
        int ixj = t ^ j;
        if (ixj > t) {
          ull a = keys[t], c2 = keys[ixj];
          bool up = ((t & k) == 0);
          if ((a > c2) == up) { keys[t] = c2; keys[ixj] = a; }
        }
      }
      __syncthreads();
    }
  }
  if (tid < PROP) {
    ull key = ~keys[tid];
    uint e = (uint)(key >> 32);
    float sc = decf(e);
    bool ok = sc > 0.5f * NEGV;
    int kk = (int)(~(uint)key);
    if (kk < 0 || kk >= NCLS * PROP) kk = 0;
    int idx = ok ? oidx[b * NCLS * PROP + kk] : 0;
    if (idx < 0) idx = 0;
    float m = ok ? 1.0f : 0.0f;
    const float* lp = logits + ((size_t)b * NN + idx) * CC;
    float* outl = out + ((size_t)b * PROP + tid) * CC;
    #pragma unroll
    for (int c = 0; c < CC; ++c) outl[c] = lp[c] * m;
    float4 bb = boxes[(size_t)b * NN + idx];
    float* outb = out + (size_t)BN * PROP * CC + ((size_t)b * PROP + tid) * 4;
    outb[0] = bb.x * m; outb[1] = bb.y * m; outb[2] = bb.z * m; outb[3] = bb.w * m;
  }
}

extern "C" void kernel_launch(void* const* d_in, const int* in_sizes, int n_in,
                              void* d_out, int out_size, void* d_ws, size_t ws_size,
                              hipStream_t stream) {
  const float* logits  = (const float*)d_in[0];  // (4,100000,41)
  const float* regress = (const float*)d_in[1];  // (4,100000,4)
  const float* anchors = (const float*)d_in[2];  // (100000,4)
  float* out = (float*)d_out;

  char* ws = (char*)d_ws;
  size_t off = 0;
  float4* boxes = (float4*)(ws + off);  off += (size_t)BN * NN * 16;
  ull* glist = (ull*)(ws + off);        off += (size_t)NPROB * LISTCAP * 8;
  ull* blist = (ull*)(ws + off);        off += (size_t)NPROB * LISTCAP * 8;
  uint* gcnt = (uint*)(ws + off);       off += NPROB * 4;
  uint* fgb  = (uint*)(ws + off);       off += BN * NBMPW * 4;
  float* osc = (float*)(ws + off);      off += NPROB * PROP * 4;
  int*   oidx = (int*)(ws + off);       off += NPROB * PROP * 4;
  uint* chist = (uint*)(ws + off);      off += (size_t)NPROB * NCHKB * 256 * 4;
  uint* gcoff = (uint*)(ws + off);      off += (size_t)NPROB * NCHKB * 256 * 4;
  uint* gC   = (uint*)(ws + off);       off += (size_t)NPROB * 257 * 4;

  decode_kernel<<<(BN * NN + 255) / 256, 256, 0, stream>>>(
      (const float4*)regress, (const float4*)anchors, boxes, gcnt);
  score_kernel<<<dim3((NN + 255) / 256, BN), 256, 0, stream>>>(logits, glist, gcnt, fgb);
  hist_kernel<<<dim3(NCHKB, NPROB), 256, 0, stream>>>(glist, gcnt, chist);
  offsets_kernel<<<NPROB, 256, 0, stream>>>(chist, gcnt, gcoff, gC);
  scatter_kernel<<<dim3(NCHKB, NPROB), 256, 0, stream>>>(glist, gcnt, gcoff, gC, blist);
  sortbins_kernel<<<dim3(256, NPROB), 256, 0, stream>>>(blist, gcnt, gC);
  nms_finish<<<NPROB, NT3, 0, stream>>>(blist, gcnt, logits, fgb, boxes, gC, oidx, osc);
  topk_kernel<<<BN, 1024, 0, stream>>>(logits, boxes, oidx, osc, out);
}

// Round 14
// 210.400 us; speedup vs baseline: 2.1263x; 1.9291x over previous
//
#include <hip/hip_runtime.h>
#include <cstdint>
#include <cstddef>

#define BN 4
#define NN 100000
#define CC 41
#define NCLS 40
#define NPROB (BN * NCLS)
#define PROP 100
#define NEGV (-1e9f)
#define IOU_T 0.3f
#define SCORE_T 0.7f
#define MAXR 4.135166556742356f
#define CAP 2048
#define TARGET 384
#define LISTCAP 26624
#define SH 4                 // gcnt shards per problem
#define SHCAP (LISTCAP / SH) // 6656
#define NBMPW 3125           // 100000/32
#define E07 0xBF333333u      // encf(0.7f)
#define ERHI 0xC1800000u     // encf(16.0f)
#define W0 ((unsigned long long)(ERHI - E07))
#define NT3 512              // threads in nms_finish

typedef unsigned long long ull;
typedef unsigned int uint;

__device__ __forceinline__ uint encf(float x) {
  uint u = __float_as_uint(x);
  return (u & 0x80000000u) ? ~u : (u | 0x80000000u);
}
__device__ __forceinline__ float decf(uint e) {
  uint u = (e & 0x80000000u) ? (e ^ 0x80000000u) : ~e;
  return __uint_as_float(u);
}
__device__ __forceinline__ uint binofE(ull E) {
  return (E >= (ull)ERHI) ? 255u : (uint)(((E - E07) << 8) / W0);
}
__device__ __forceinline__ ull edgeE(int b) {   // low edge of bin b
  return (ull)E07 + (((ull)b * W0 + 255ull) >> 8);
}

__device__ __forceinline__ float iou_f(float ax1, float ay1, float ax2, float ay2,
                                       float bx1, float by1, float bx2, float by2) {
  float ix1 = fmaxf(ax1, bx1), iy1 = fmaxf(ay1, by1);
  float ix2 = fminf(ax2, bx2), iy2 = fminf(ay2, by2);
  float inter = fmaxf(ix2 - ix1, 0.0f) * fmaxf(iy2 - iy1, 0.0f);
  float a1 = (ax2 - ax1) * (ay2 - ay1);
  float a2 = (bx2 - bx1) * (by2 - by1);
  return inter / fmaxf(a1 + a2 - inter, 1e-9f);
}

// serial selection from a 256-bin histogram (rare fallback path only)
__device__ __forceinline__ int select_window(const uint* h, int* lo_out) {
  uint cum = 0; int lo = 256; int act = 2;
  for (int bb = 255; bb >= 0; --bb) {
    uint nb = h[bb];
    if (nb == 0u) continue;
    if (cum + nb > CAP) {
      if (cum == 0u) { act = 1; }
      break;
    }
    cum += nb; lo = bb; act = 0;
    if (cum >= TARGET) break;
  }
  *lo_out = lo;
  return act;
}

// ---------------- Kernel A: decode + clip boxes, zero counters ----------------
__global__ void decode_kernel(const float4* __restrict__ regress,
                              const float4* __restrict__ anchors,
                              float4* __restrict__ boxes,
                              uint* __restrict__ gcnt) {
  int i = blockIdx.x * 256 + threadIdx.x;
  if (i < NPROB * SH) gcnt[i] = 0u;
  if (i >= BN * NN) return;
  int n = i % NN;
  float4 d = regress[i];
  float4 a = anchors[n];
  float w = a.z - a.x, h = a.w - a.y;
  float cx = a.x + 0.5f * w, cy = a.y + 0.5f * h;
  float dx = d.x * 0.1f, dy = d.y * 0.1f;
  float dw = fminf(fmaxf(d.z * 0.2f, -MAXR), MAXR);
  float dh = fminf(fmaxf(d.w * 0.2f, -MAXR), MAXR);
  float pcx = cx + dx * w, pcy = cy + dy * h;
  float pw = w * expf(dw), ph = h * expf(dh);
  float4 o;
  o.x = fminf(fmaxf(pcx - 0.5f * pw, 0.0f), 1.0f);
  o.y = fminf(fmaxf(pcy - 0.5f * ph, 0.0f), 1.0f);
  o.z = fminf(fmaxf(pcx + 0.5f * pw, 0.0f), 1.0f);
  o.w = fminf(fmaxf(pcy + 0.5f * ph, 0.0f), 1.0f);
  boxes[i] = o;
}

// ---------------- Kernel B: fg + sharded per-problem compact candidate lists ----------------
__global__ void score_kernel(const float* __restrict__ logits,
                             ull* __restrict__ glist,
                             uint* __restrict__ gcnt,
                             uint* __restrict__ fgb) {
  __shared__ float lg[256 * CC];            // 42 KB
  __shared__ unsigned short wpre[NCLS][4];
  __shared__ uint cbase[NCLS];
  int b = blockIdx.y;
  int n0 = blockIdx.x * 256;
  int shard = blockIdx.x & (SH - 1);
  int tid = threadIdx.x;
  int wave = tid >> 6, lane = tid & 63;
  int rows = NN - n0; if (rows > 256) rows = 256;
  int total4 = rows * CC / 4;
  const float4* src = (const float4*)(logits + ((size_t)b * NN + n0) * CC);
  float4* dst = (float4*)lg;
  for (int i = tid; i < total4; i += 256) dst[i] = src[i];
  __syncthreads();

  bool act = tid < rows;
  int n = n0 + tid;
  float bestv = 0.0f; int bestc = 0;
  if (act) {
    bestv = lg[tid * CC];
    #pragma unroll
    for (int c = 1; c < CC; ++c) {
      float v = lg[tid * CC + c];
      if (v > bestv) { bestv = v; bestc = c; }
    }
  }
  bool fg = act && (bestc > 0);
  int wbase = n0 + (tid & ~63);

  ull mfg = __ballot(fg);
  if (lane == 0 && wbase < NN) fgb[b * NBMPW + (wbase >> 5)] = (uint)mfg;
  if (lane == 32 && wbase + 32 < NN) fgb[b * NBMPW + (wbase >> 5) + 1] = (uint)(mfg >> 32);

  #pragma unroll 4
  for (int c = 1; c < CC; ++c) {
    float v = act ? lg[tid * CC + c] : 0.0f;
    ull m = __ballot(fg && (v >= SCORE_T));
    if (lane == 0) wpre[c - 1][wave] = (unsigned short)__popcll(m);
  }
  __syncthreads();

  if (tid < NCLS) {
    uint t0 = wpre[tid][0], t1 = wpre[tid][1], t2 = wpre[tid][2], t3 = wpre[tid][3];
    uint tot = t0 + t1 + t2 + t3;
    uint base = tot ? atomicAdd(&gcnt[(b * NCLS + tid) * SH + shard], tot) : 0u;
    cbase[tid] = base;
    wpre[tid][0] = 0;
    wpre[tid][1] = (unsigned short)t0;
    wpre[tid][2] = (unsigned short)(t0 + t1);
    wpre[tid][3] = (unsigned short)(t0 + t1 + t2);
  }
  __syncthreads();

  #pragma unroll 4
  for (int c = 1; c < CC; ++c) {
    float v = act ? lg[tid * CC + c] : 0.0f;
    bool elig = fg && (v >= SCORE_T);
    ull m = __ballot(elig);
    if (elig) {
      uint pos = cbase[c - 1] + wpre[c - 1][wave]
               + (uint)__popcll(m & ((1ull << lane) - 1ull));
      if (pos < SHCAP)
        glist[(size_t)(b * NCLS + (c - 1)) * LISTCAP + (size_t)shard * SHCAP + pos] =
            ((ull)encf(v) << 32) | (uint)n;
    }
  }
}

// ---------------- Kernel C1: per-(problem,shard) 256-bin histogram ----------------
__global__ void hist_kernel(const ull* __restrict__ glist,
                            const uint* __restrict__ gcnt,
                            uint* __restrict__ chist) {
  __shared__ uint h[256];
  int prob = blockIdx.y;
  int shard = blockIdx.x;
  int tid = threadIdx.x;
  uint cs = gcnt[prob * SH + shard];
  if (cs > SHCAP) cs = SHCAP;   // dense case: downstream ignores hist anyway
  h[tid] = 0u;
  __syncthreads();
  uint lo = shard * SHCAP;
  uint hi = lo + cs;
  const ull* list = glist + (size_t)prob * LISTCAP;
  for (uint i = lo + tid; i < hi; i += 256)
    atomicAdd(&h[binofE(list[i] >> 32)], 1u);
  __syncthreads();
  chist[((size_t)prob * SH + shard) * 256 + tid] = h[tid];
}

// ---------------- Kernel C2: per-problem offsets (suffix-scan + shard prefixes) ----------------
__global__ void offsets_kernel(const uint* __restrict__ chist,
                               const uint* __restrict__ gcnt,
                               uint* __restrict__ gcoff,
                               uint* __restrict__ gC,
                               uint* __restrict__ gtot) {
  __shared__ uint sa[256], sb[256];
  int prob = blockIdx.x;
  int tid = threadIdx.x;
  uint c0 = gcnt[prob * SH + 0], c1 = gcnt[prob * SH + 1],
       c2 = gcnt[prob * SH + 2], c3 = gcnt[prob * SH + 3];
  bool dense = (c0 > SHCAP) || (c1 > SHCAP) || (c2 > SHCAP) || (c3 > SHCAP);
  if (tid == 0) gtot[prob] = dense ? (LISTCAP + 1u) : (c0 + c1 + c2 + c3);
  if (dense) return;
  const uint* ch = chist + (size_t)prob * SH * 256;
  uint h0 = ch[0 * 256 + tid], h1 = ch[1 * 256 + tid],
       h2 = ch[2 * 256 + tid], h3 = ch[3 * 256 + tid];
  gcoff[((size_t)prob * SH + 0) * 256 + tid] = 0u;
  gcoff[((size_t)prob * SH + 1) * 256 + tid] = h0;
  gcoff[((size_t)prob * SH + 2) * 256 + tid] = h0 + h1;
  gcoff[((size_t)prob * SH + 3) * 256 + tid] = h0 + h1 + h2;
  sa[tid] = h0 + h1 + h2 + h3;
  __syncthreads();
  uint* s = sa; uint* d = sb;
  for (int off = 1; off < 256; off <<= 1) {
    uint v = s[tid] + ((tid + off < 256) ? s[tid + off] : 0u);
    d[tid] = v;
    __syncthreads();
    uint* t = s; s = d; d = t;
  }
  gC[(size_t)prob * 257 + tid] = s[tid];   // C[bin] = #elements in bins >= bin
  if (tid == 0) gC[(size_t)prob * 257 + 256] = 0u;
}

// ---------------- Kernel C3: counting-sort scatter into bucketed list ----------------
__global__ void scatter_kernel(const ull* __restrict__ glist,
                               const uint* __restrict__ gcnt,
                               const uint* __restrict__ gcoff,
                               const uint* __restrict__ gC,
                               const uint* __restrict__ gtot,
                               ull* __restrict__ blist) {
  __shared__ uint rank[256], startL[256], cofL[256];
  int prob = blockIdx.y;
  int shard = blockIdx.x;
  int tid = threadIdx.x;
  if (gtot[prob] > LISTCAP) return;   // dense
  uint cs = gcnt[prob * SH + shard];
  rank[tid] = 0u;
  cofL[tid] = gcoff[((size_t)prob * SH + shard) * 256 + tid];
  startL[tid] = gC[(size_t)prob * 257 + tid + 1];   // start of bin's run
  __syncthreads();
  uint lo = shard * SHCAP;
  uint hi = lo + cs;
  const ull* list = glist + (size_t)prob * LISTCAP;
  ull* bl = blist + (size_t)prob * LISTCAP;
  for (uint i = lo + tid; i < hi; i += 256) {
    ull k = list[i];
    uint bin = binofE(k >> 32);
    uint r = atomicAdd(&rank[bin], 1u);
    bl[startL[bin] + cofL[bin] + r] = k;
  }
}

// ---------------- sort + walk (shared) ----------------
__device__ int sort_walk(int ncand, int nsel,
                         ull* keysL, float4* boxesL, float4* selL,
                         int* sh_nsel, int prob, int* __restrict__ oidx,
                         float* __restrict__ osc, int tid) {
  if (ncand == 0) return nsel;
  int M = 64; while (M < ncand) M <<= 1;
  for (int i = ncand + tid; i < M; i += NT3) keysL[i] = 0ull;
  __syncthreads();
  for (int k = 2; k <= M; k <<= 1) {
    for (int j = k >> 1; j > 0; j >>= 1) {
      for (int t = tid; t < M; t += NT3) {
        int ixj = t ^ j;
        if (ixj > t) {
          ull a = keysL[t], c2 = keysL[ixj];
          bool up = ((t & k) == 0);     // up-region: descending
          if (up ? (a < c2) : (a > c2)) { keysL[t] = c2; keysL[ixj] = a; }
        }
      }
      __syncthreads();
    }
  }
  if (tid < 64) {
    int lane = tid;
    int ns = nsel;
    for (int base = 0; base < ncand && ns < PROP; base += 64) {
      int i = base + lane;
      bool valid = i < ncand;
      ull key = valid ? keysL[i] : 0ull;
      int slot = (int)(key & 0x7FFF);
      float4 bx = boxesL[valid ? slot : 0];
      float sc = decf((uint)(key >> 32));
      int aidx = 131071 - (int)((key >> 15) & 0x1FFFF);
      bool supp = false;
      for (int j = 0; j < ns; ++j) {
        float4 sb = selL[j];
        supp = supp || (iou_f(bx.x, bx.y, bx.z, bx.w, sb.x, sb.y, sb.z, sb.w) > IOU_T);
      }
      ull live = __ballot(valid && !supp);
      while (live && ns < PROP) {
        int kk = __ffsll(live) - 1;
        float x1 = __shfl(bx.x, kk), y1 = __shfl(bx.y, kk);
        float x2 = __shfl(bx.z, kk), y2 = __shfl(bx.w, kk);
        float ksc = __shfl(sc, kk);
        int kidx = __shfl(aidx, kk);
        if (lane == 0) {
          oidx[prob * PROP + ns] = kidx;
          osc [prob * PROP + ns] = ksc;
          selL[ns] = make_float4(x1, y1, x2, y2);
        }
        ns++;
        if (lane > kk && valid && !supp)
          supp = iou_f(bx.x, bx.y, bx.z, bx.w, x1, y1, x2, y2) > IOU_T;
        live = __ballot(valid && !supp) & ~((2ull << kk) - 1ull);
      }
    }
    if (lane == 0) *sh_nsel = ns;
  }
  __syncthreads();
  return *sh_nsel;
}

// ---------------- compact + sort + walk one window (fallback path) ----------------
__device__ int process_window(ull WLO, ull WUP, int idxbin,
                              bool dense, uint rs, uint re,
                              const ull* list, const float* lcol,
                              const uint* fgp, const float4* bx4,
                              ull* keysL, float4* boxesL, float4* selL,
                              int* sh_cnt, int* sh_nsel,
                              int nsel, int prob, int* __restrict__ oidx,
                              float* __restrict__ osc, int tid) {
  __syncthreads();
  if (tid == 0) *sh_cnt = 0;
  __syncthreads();
  if (!dense) {
    for (uint i = rs + tid; i < re; i += NT3) {
      ull k = list[i];
      ull E = k >> 32;
      uint idx = (uint)(k & 0xFFFFFFFFu);
      if (E >= WLO && E < WUP && (idxbin < 0 || (int)(idx >> 9) == idxbin)) {
        int slot = atomicAdd(sh_cnt, 1);
        if (slot < CAP) {
          keysL[slot] = (E << 32)
                      | ((ull)((131071u - idx) & 0x1FFFFu) << 15)
                      | (ull)slot;
          boxesL[slot] = bx4[idx];
        }
      }
    }
  } else {
    for (int i = tid; i < NN; i += NT3) {
      if (!((fgp[i >> 5] >> (i & 31)) & 1u)) continue;
      float s = lcol[(size_t)i * CC];
      if (s < SCORE_T) continue;
      ull E = encf(s);
      if (E >= WLO && E < WUP && (idxbin < 0 || (i >> 9) == idxbin)) {
        int slot = atomicAdd(sh_cnt, 1);
        if (slot < CAP) {
          keysL[slot] = (E << 32)
                      | ((ull)((131071u - (uint)i) & 0x1FFFFu) << 15)
                      | (ull)slot;
          boxesL[slot] = bx4[i];
        }
      }
    }
  }
  __syncthreads();
  int ncand = *sh_cnt; if (ncand > CAP) ncand = CAP;
  return sort_walk(ncand, nsel, keysL, boxesL, selL, sh_nsel, prob, oidx, osc, tid);
}

// ---------------- exact processing of encoded range [Rlo0, Rhi0) ----------------
__device__ int fallback_range(ull Rlo0, ull Rhi0,
                              bool dense, uint rs, uint re,
                              const ull* list, const float* lcol,
                              const uint* fgp, const float4* bx4,
                              ull* keysL, float4* boxesL, float4* selL,
                              uint* subh,
                              int* sh_cnt, int* sh_nsel, int* sh_a, int* sh_b,
                              int nsel, int prob, int* __restrict__ oidx,
                              float* __restrict__ osc, int tid) {
  ull EHIl = Rhi0;
  for (int round = 0; round < 300 && nsel < PROP; ++round) {
    ull Rlo = Rlo0, Rhi = EHIl;
    int action; int bsel;
    ull WLO = 0, WUP = 0, E0 = 0;
    bool idxm = false;
    while (true) {
      for (int i = tid; i < 256; i += NT3) subh[i] = 0u;
      __syncthreads();
      ull W = Rhi - Rlo;
      if (!dense) {
        for (uint i = rs + tid; i < re; i += NT3) {
          ull E = list[i] >> 32;
          if (E >= Rlo && E < Rhi)
            atomicAdd(&subh[(uint)(((E - Rlo) << 8) / W)], 1u);
        }
      } else {
        for (int i = tid; i < NN; i += NT3) {
          if (!((fgp[i >> 5] >> (i & 31)) & 1u)) continue;
          float s = lcol[(size_t)i * CC];
          if (s < SCORE_T) continue;
          ull E = encf(s);
          if (E >= Rlo && E < Rhi)
            atomicAdd(&subh[(uint)(((E - Rlo) << 8) / W)], 1u);
        }
      }
      __syncthreads();
      if (tid == 0) {
        int lo;
        int act = select_window(subh, &lo);
        int rb = -1;
        if (act == 1) {
          for (int bb = 255; bb >= 0; --bb) if (subh[bb]) { rb = bb; break; }
        }
        *sh_a = act; *sh_b = (act == 1) ? rb : lo;
      }
      __syncthreads();
      action = *sh_a; bsel = *sh_b;
      __syncthreads();
      if (action == 2) break;
      if (action == 0) {
        WLO = Rlo + (((ull)bsel * W + 255ull) >> 8);
        WUP = Rhi;
        break;
      }
      ull nRlo = Rlo + (((ull)bsel * W + 255ull) >> 8);
      ull nRhi = Rlo + (((ull)(bsel + 1) * W + 255ull) >> 8);
      if (nRhi > Rhi) nRhi = Rhi;
      Rlo = nRlo; Rhi = nRhi;
      if (Rhi - Rlo <= 1ull) { idxm = true; E0 = Rlo; break; }
    }
    if (action == 2) break;
    if (!idxm) {
      nsel = process_window(WLO, WUP, -1, dense, rs, re, list, lcol, fgp, bx4,
                            keysL, boxesL, selL, sh_cnt, sh_nsel,
                            nsel, prob, oidx, osc, tid);
      EHIl = WLO;
    } else {
      for (int ib = 0; ib < 256 && nsel < PROP; ++ib)
        nsel = process_window(E0, E0 + 1ull, ib, dense, rs, re, list, lcol, fgp, bx4,
                              keysL, boxesL, selL, sh_cnt, sh_nsel,
                              nsel, prob, oidx, osc, tid);
      EHIl = E0;
    }
  }
  return nsel;
}

// ---------------- Kernel C4: windowed sorted-walk NMS over bucketed list ----------------
__launch_bounds__(NT3)
__global__ void nms_finish(const ull* __restrict__ blist,
                           const uint* __restrict__ gtot,
                           const float* __restrict__ logits,
                           const uint* __restrict__ fgb,
                           const float4* __restrict__ boxes,
                           const uint* __restrict__ gC,
                           int* __restrict__ oidx, float* __restrict__ osc) {
  __shared__ uint CL[257];
  __shared__ uint subh[256];
  __shared__ ull keysL[CAP];                // 16 KB
  __shared__ float4 boxesL[CAP];            // 32 KB
  __shared__ float4 selL[PROP];
  __shared__ int sh_cnt, sh_nsel, sh_a, sh_b, sh_m;

  int prob = blockIdx.x;
  int b = prob / NCLS;
  int c1 = prob % NCLS + 1;
  int tid = threadIdx.x;

  uint cnt = gtot[prob];
  bool dense = cnt > LISTCAP;
  const ull* bl = blist + (size_t)prob * LISTCAP;
  const float4* bx4 = boxes + (size_t)b * NN;
  const float* lcol = logits + (size_t)b * NN * CC + c1;
  const uint* fgp = fgb + b * NBMPW;

  int nsel = 0;

  if (dense) {
    nsel = fallback_range(E07, 1ull << 32, true, 0, 0, bl, lcol, fgp, bx4,
                          keysL, boxesL, selL, subh,
                          &sh_cnt, &sh_nsel, &sh_a, &sh_b,
                          0, prob, oidx, osc, tid);
  } else {
    for (int i = tid; i < 257; i += NT3) CL[i] = gC[(size_t)prob * 257 + i];
    __syncthreads();
    int hibin = 256;
    while (nsel < PROP && hibin > 0) {
      if (tid == 0) sh_m = -1;
      __syncthreads();
      if (tid < 256 && tid < hibin && (CL[tid] - CL[hibin]) >= TARGET)
        atomicMax(&sh_m, tid);
      __syncthreads();
      if (tid == 0) {
        int bm = sh_m; int act, lo;
        if (bm < 0) {
          uint W = CL[0] - CL[hibin];
          act = W ? 0 : 2; lo = 0;
        } else {
          uint W = CL[bm] - CL[hibin];
          if (W <= CAP) { act = 0; lo = bm; }
          else {
            uint W2 = CL[bm + 1] - CL[hibin];
            if (W2) { act = 0; lo = bm + 1; }
            else { act = 1; lo = bm; }
          }
        }
        sh_a = act; sh_b = lo;
      }
      __syncthreads();
      int act = sh_a, lo = sh_b;
      __syncthreads();
      if (act == 2) break;
      if (act == 0) {
        uint rs = CL[hibin];
        int ncand = (int)(CL[lo] - CL[hibin]);
        for (int i = tid; i < ncand; i += NT3) {
          ull k = bl[rs + i];
          uint idx = (uint)(k & 0xFFFFFFFFu);
          keysL[i] = ((k >> 32) << 32)
                   | ((ull)((131071u - idx) & 0x1FFFFu) << 15)
                   | (ull)i;
          boxesL[i] = bx4[idx];
        }
        __syncthreads();
        nsel = sort_walk(ncand, nsel, keysL, boxesL, selL, &sh_nsel, prob, oidx, osc, tid);
        hibin = lo;
      } else {
        // refine: single bin 'lo' exceeds CAP — contiguous run, value-refined exactly
        uint rs = CL[lo + 1], re = CL[lo];
        ull Rlo = edgeE(lo);
        ull Rhi = (lo == 255) ? (1ull << 32) : edgeE(lo + 1);
        nsel = fallback_range(Rlo, Rhi, false, rs, re, bl, lcol, fgp, bx4,
                              keysL, boxesL, selL, subh,
                              &sh_cnt, &sh_nsel, &sh_a, &sh_b,
                              nsel, prob, oidx, osc, tid);
        hibin = lo;
      }
    }
  }

  __syncthreads();
  for (int p = nsel + tid; p < PROP; p += NT3) {
    oidx[prob * PROP + p] = -1;
    osc [prob * PROP + p] = NEGV;
  }
}

// ---------------- Kernel D: per-batch top-100 of 4000 (bitonic, 1024 thr) + gather ----------------
__global__ void topk_kernel(const float* __restrict__ logits,
                            const float4* __restrict__ boxes,
                            const int* __restrict__ oidx,
                            const float* __restrict__ osc,
                            float* __restrict__ out) {
  __shared__ ull keys[4096];  // 32 KB
  int b = blockIdx.x;
  int tid = threadIdx.x;
  for (int i = tid; i < 4096; i += 1024) {
    ull key = 0ull;
    if (i < NCLS * PROP) {
      float sc = osc[b * NCLS * PROP + i];
      key = ((ull)encf(sc) << 32) | (uint)(~i);
    }
    keys[i] = ~key;
  }
  __syncthreads();
  for (int k = 2; k <= 4096; k <<= 1) {
    for (int j = k >> 1; j > 0; j >>= 1) {
      for (int t = tid; t < 4096; t += 1024) {
        int ixj = t ^ j;
        if (ixj > t) {
          ull a = keys[t], c2 = keys[ixj];
          bool up = ((t & k) == 0);
          if ((a > c2) == up) { keys[t] = c2; keys[ixj] = a; }
        }
      }
      __syncthreads();
    }
  }
  if (tid < PROP) {
    ull key = ~keys[tid];
    uint e = (uint)(key >> 32);
    float sc = decf(e);
    bool ok = sc > 0.5f * NEGV;
    int kk = (int)(~(uint)key);
    if (kk < 0 || kk >= NCLS * PROP) kk = 0;
    int idx = ok ? oidx[b * NCLS * PROP + kk] : 0;
    if (idx < 0) idx = 0;
    float m = ok ? 1.0f : 0.0f;
    const float* lp = logits + ((size_t)b * NN + idx) * CC;
    float* outl = out + ((size_t)b * PROP + tid) * CC;
    #pragma unroll
    for (int c = 0; c < CC; ++c) outl[c] = lp[c] * m;
    float4 bb = boxes[(size_t)b * NN + idx];
    float* outb = out + (size_t)BN * PROP * CC + ((size_t)b * PROP + tid) * 4;
    outb[0] = bb.x * m; outb[1] = bb.y * m; outb[2] = bb.z * m; outb[3] = bb.w * m;
  }
}

extern "C" void kernel_launch(void* const* d_in, const int* in_sizes, int n_in,
                              void* d_out, int out_size, void* d_ws, size_t ws_size,
                              hipStream_t stream) {
  const float* logits  = (const float*)d_in[0];  // (4,100000,41)
  const float* regress = (const float*)d_in[1];  // (4,100000,4)
  const float* anchors = (const float*)d_in[2];  // (100000,4)
  float* out = (float*)d_out;

  char* ws = (char*)d_ws;
  size_t off = 0;
  float4* boxes = (float4*)(ws + off);  off += (size_t)BN * NN * 16;
  ull* glist = (ull*)(ws + off);        off += (size_t)NPROB * LISTCAP * 8;
  ull* blist = (ull*)(ws + off);        off += (size_t)NPROB * LISTCAP * 8;
  uint* gcnt = (uint*)(ws + off);       off += NPROB * SH * 4;
  uint* gtot = (uint*)(ws + off);       off += NPROB * 4;
  uint* fgb  = (uint*)(ws + off);       off += BN * NBMPW * 4;
  float* osc = (float*)(ws + off);      off += NPROB * PROP * 4;
  int*   oidx = (int*)(ws + off);       off += NPROB * PROP * 4;
  uint* chist = (uint*)(ws + off);      off += (size_t)NPROB * SH * 256 * 4;
  uint* gcoff = (uint*)(ws + off);      off += (size_t)NPROB * SH * 256 * 4;
  uint* gC   = (uint*)(ws + off);       off += (size_t)NPROB * 257 * 4;

  decode_kernel<<<(BN * NN + 255) / 256, 256, 0, stream>>>(
      (const float4*)regress, (const float4*)anchors, boxes, gcnt);
  score_kernel<<<dim3((NN + 255) / 256, BN), 256, 0, stream>>>(logits, glist, gcnt, fgb);
  hist_kernel<<<dim3(SH, NPROB), 256, 0, stream>>>(glist, gcnt, chist);
  offsets_kernel<<<NPROB, 256, 0, stream>>>(chist, gcnt, gcoff, gC, gtot);
  scatter_kernel<<<dim3(SH, NPROB), 256, 0, stream>>>(glist, gcnt, gcoff, gC, gtot, blist);
  nms_finish<<<NPROB, NT3, 0, stream>>>(blist, gtot, logits, fgb, boxes, gC, oidx, osc);
  topk_kernel<<<BN, 1024, 0, stream>>>(logits, boxes, oidx, osc, out);
}